// Round 10
// baseline (217.677 us; speedup 1.0000x reference)
//
#include <hip/hip_runtime.h>
#include <hip/hip_bf16.h>

// PAM module R10: q/k/v 1x1 projections -> bf16 MFMA attention -> gamma*out + x.
// R9 post-mortem: all pipes serialized (sum 7300 cyc/body = measured 7387); the
// body's single dependency chain S->exp->bperm->PV never overlaps pipes.
// R10: cross-body software pipeline. Each body issues S(i+1) and PV(i) as
// INTERLEAVED independent MFMA streams; exp+bperm(i+1) -> carried pf feeds PV in
// the next body. K DMA'd 2 tiles ahead, V 1 ahead (hazard-free with 2 buffers
// each). Q's ni1 half lives in LDS (register relief: fits 2 waves/SIMD, no
// spill). exp2f with log2(e) folded into q weights in proj.
//
// 32x32x16 layouts (R9-verified):
//   A[i][k]: i = lane&31, k = (lane>>5)*8 + e;  B same;  C/D: col = lane&31,
//   row = (reg&3) + 8*(reg>>2) + 4*(lane>>5)
// Workspace (bf16, frag-major, unchanged from R9):
//   qf_ws[b][strip64][ni2][kc8][lane]{8}   8MB
//   kt   [b][sub64][mh2][kc8][lane]{8}     8MB
//   vt   [b][sub64][cb4][km4][lane]{8}     8MB

typedef __bf16 v8bf __attribute__((ext_vector_type(8)));
typedef float  v4f  __attribute__((ext_vector_type(4)));
typedef float  v16f __attribute__((ext_vector_type(16)));
typedef __attribute__((address_space(3))) void       lds_v;
typedef const __attribute__((address_space(1))) void gbl_v;

#define B_ 8
#define C_ 128
#define N_ 4096
#define LOG2E 1.4426950408889634f

static __device__ __forceinline__ unsigned short f2bf_rne(float f) {
    union { float f; unsigned u; } v; v.f = f;
    return (unsigned short)((v.u + 0x7fffu + ((v.u >> 16) & 1u)) >> 16);
}
static __device__ __forceinline__ unsigned fbits(float f) {
    union { float f; unsigned u; } v; v.f = f; return v.u;
}

// ---------------------------------------------------------------------------
// Kernel 1: one block per (b, tile128). 256 thr / 4 waves. x staged once,
// 3 weight GEMMs; frag-major scatter for the 32x32 attention layouts.
// Only change vs R9: q weights folded with LOG2E (softmax via exp2).
// ---------------------------------------------------------------------------
__global__ __launch_bounds__(256, 2) void proj_kernel(
    const float* __restrict__ x,
    const float* __restrict__ dw_q, const float* __restrict__ pw_q,
    const float* __restrict__ dw_k, const float* __restrict__ pw_k,
    const float* __restrict__ dw_v, const float* __restrict__ pw_v,
    unsigned short* __restrict__ qf_ws, unsigned short* __restrict__ kt,
    unsigned short* __restrict__ vt)
{
    __shared__ unsigned short xT[128 * 136];
    __shared__ unsigned short Ws[128 * 136];

    const int bid = blockIdx.x;
    const int bb  = bid & 7;
    const int t   = bid >> 3;
    const int n0  = t * 128;
    const int tid = threadIdx.x;
    const int w    = tid >> 6;
    const int lane = tid & 63;
    const int quad = lane >> 4;
    const int l16  = lane & 15;

    #pragma unroll
    for (int k = 0; k < 16; ++k) {
        const int idx = tid + k * 256;
        const int c  = idx >> 5;
        const int nq = idx & 31;
        float4 f = *(const float4*)(x + ((size_t)(bb * C_ + c)) * N_ + n0 + nq * 4);
        xT[(nq * 4 + 0) * 136 + c] = f2bf_rne(f.x);
        xT[(nq * 4 + 1) * 136 + c] = f2bf_rne(f.y);
        xT[(nq * 4 + 2) * 136 + c] = f2bf_rne(f.z);
        xT[(nq * 4 + 3) * 136 + c] = f2bf_rne(f.w);
    }

    for (int pp = 0; pp < 3; ++pp) {
        __syncthreads();

        const float* pw = (pp == 0) ? pw_q : (pp == 1) ? pw_k : pw_v;
        const float* dw = (pp == 0) ? dw_q : (pp == 1) ? dw_k : dw_v;
        const float wsc = (pp == 0) ? LOG2E : 1.0f;   // softmax via exp2
        #pragma unroll
        for (int k = 0; k < 16; ++k) {
            const int idx = tid + k * 256;
            const int o  = idx >> 5;
            const int c4 = (idx & 31) * 4;
            float4 p4 = *(const float4*)(pw + o * 128 + c4);
            float4 d4 = *(const float4*)(dw + c4);
            unsigned lo = (unsigned)f2bf_rne(p4.x * d4.x * wsc) | ((unsigned)f2bf_rne(p4.y * d4.y * wsc) << 16);
            unsigned hi = (unsigned)f2bf_rne(p4.z * d4.z * wsc) | ((unsigned)f2bf_rne(p4.w * d4.w * wsc) << 16);
            *(unsigned long long*)&Ws[o * 136 + c4] =
                (unsigned long long)lo | ((unsigned long long)hi << 32);
        }
        __syncthreads();

        const unsigned short* As = (pp < 2) ? xT : Ws;
        const unsigned short* Bs = (pp < 2) ? Ws : xT;

        v4f acc[2][8];
        #pragma unroll
        for (int i = 0; i < 2; ++i)
            #pragma unroll
            for (int j = 0; j < 8; ++j)
                acc[i][j] = (v4f){0.f, 0.f, 0.f, 0.f};

        #pragma unroll
        for (int kc = 0; kc < 4; ++kc) {
            v8bf av[2];
            #pragma unroll
            for (int i = 0; i < 2; ++i)
                av[i] = *(const v8bf*)&As[(w * 32 + i * 16 + l16) * 136 + kc * 32 + quad * 8];
            #pragma unroll
            for (int cb = 0; cb < 8; ++cb) {
                v8bf bv = *(const v8bf*)&Bs[(cb * 16 + l16) * 136 + kc * 32 + quad * 8];
                acc[0][cb] = __builtin_amdgcn_mfma_f32_16x16x32_bf16(av[0], bv, acc[0][cb], 0, 0, 0);
                acc[1][cb] = __builtin_amdgcn_mfma_f32_16x16x32_bf16(av[1], bv, acc[1][cb], 0, 0, 0);
            }
        }
        __syncthreads();

        unsigned short* sc = Ws;
        #pragma unroll
        for (int mi = 0; mi < 2; ++mi)
            #pragma unroll
            for (int cb = 0; cb < 8; ++cb)
                #pragma unroll
                for (int r = 0; r < 4; ++r)
                    sc[(w * 32 + mi * 16 + quad * 4 + r) * 136 + cb * 16 + l16] =
                        f2bf_rne(acc[mi][cb][r]);
        __syncthreads();

        if (pp == 0) {
            unsigned short* dst = qf_ws + ((size_t)(bb * 64 + t * 2)) * 8192;
            #pragma unroll
            for (int p = 0; p < 8; ++p) {
                const int u  = p * 256 + tid;
                const int lu = u & 63, kc = (u >> 6) & 7, ni = (u >> 9) & 1, st = u >> 10;
                const int row = st * 64 + ni * 32 + (lu & 31);
                const int col = kc * 16 + (lu >> 5) * 8;
                *(uint4*)(dst + (size_t)u * 8) = *(const uint4*)&sc[row * 136 + col];
            }
        } else if (pp == 1) {
            unsigned short* dst = kt + ((size_t)(bb * 64 + t * 2)) * 8192;
            #pragma unroll
            for (int p = 0; p < 8; ++p) {
                const int u  = p * 256 + tid;
                const int lu = u & 63, kc = (u >> 6) & 7, mh = (u >> 9) & 1, st = u >> 10;
                const int row = st * 64 + mh * 32 + (lu & 31);
                const int col = kc * 16 + (lu >> 5) * 8;
                *(uint4*)(dst + (size_t)u * 8) = *(const uint4*)&sc[row * 136 + col];
            }
        } else {
            unsigned short* dst = vt + ((size_t)(bb * 64 + t * 2)) * 8192;
            #pragma unroll
            for (int p = 0; p < 8; ++p) {
                const int u  = p * 256 + tid;
                const int lu = u & 63, km = (u >> 6) & 3, cb = (u >> 8) & 3, st = u >> 10;
                const int row = cb * 32 + (lu & 31);
                const int col = st * 64 + km * 16 + (lu >> 5) * 8;
                *(uint4*)(dst + (size_t)u * 8) = *(const uint4*)&sc[row * 136 + col];
            }
        }
    }
}

// ---------------------------------------------------------------------------
// Kernel 2: attention. grid 256 = (b, 128-n strip). 512 thr / 8 waves =
// 4 mq x 2 nh. Cross-body pipeline: body i = { barrier; DMA K(i+2), V(i+1);
// fused loop [S(i+1) + PV(i) interleaved]; exp(i+1); bperm -> pf }.
// ---------------------------------------------------------------------------
#define DMAKT(TILE, OFF) { \
    const unsigned short* ks_ = ktb + (size_t)(TILE) * 16384; \
    _Pragma("unroll") \
    for (int i_ = 0; i_ < 4; ++i_) { \
        const int u_ = i_ * 512 + tid; \
        __builtin_amdgcn_global_load_lds((gbl_v*)(ks_ + (size_t)u_ * 8), \
                                         (lds_v*)(kbuf + (OFF) + u_ * 8), 16, 0, 0); \
    } \
}
#define DMAVT(TILE, OFF) { \
    const unsigned short* vs_ = vtb + (size_t)(TILE) * 16384; \
    _Pragma("unroll") \
    for (int i_ = 0; i_ < 4; ++i_) { \
        const int u_ = i_ * 512 + tid; \
        __builtin_amdgcn_global_load_lds((gbl_v*)(vs_ + (size_t)u_ * 8), \
                                         (lds_v*)(vbuf + (OFF) + u_ * 8), 16, 0, 0); \
    } \
}

#define FUSED(KOFF, VOFF, DO_S, DO_PV) { \
    const unsigned short* kpb_ = kbuf + (KOFF) + mq * 4096 + lane * 8; \
    const unsigned short* vpb_ = vbuf + (VOFF) + vwoff + lane * 8; \
    v16f s0_, s1_; \
    _Pragma("unroll") \
    for (int r_ = 0; r_ < 16; ++r_) { s0_[r_] = 0.f; s1_[r_] = 0.f; } \
    _Pragma("unroll") \
    for (int j_ = 0; j_ < 8; ++j_) { \
        if (DO_S) { \
            v8bf kf_ = *(const v8bf*)(kpb_ + j_ * 512); \
            v8bf q1_ = *(const v8bf*)(qlds + nh * 4096 + j_ * 512 + lane * 8); \
            s0_ = __builtin_amdgcn_mfma_f32_32x32x16_bf16(kf_, qf0[j_], s0_, 0, 0, 0); \
            s1_ = __builtin_amdgcn_mfma_f32_32x32x16_bf16(kf_, q1_, s1_, 0, 0, 0); \
        } \
        if (DO_PV) { \
            v8bf vf_ = *(const v8bf*)(vpb_ + ((j_ >> 1) * 4 + (j_ & 1)) * 512); \
            oacc[j_ >> 1][0] = __builtin_amdgcn_mfma_f32_32x32x16_bf16(vf_, pf[j_ & 1][0], oacc[j_ >> 1][0], 0, 0, 0); \
            oacc[j_ >> 1][1] = __builtin_amdgcn_mfma_f32_32x32x16_bf16(vf_, pf[j_ & 1][1], oacc[j_ >> 1][1], 0, 0, 0); \
        } \
    } \
    if (DO_S) { \
        unsigned pk_[2][4][2]; \
        _Pragma("unroll") \
        for (int ni_ = 0; ni_ < 2; ++ni_) { \
            float e_[16]; \
            _Pragma("unroll") \
            for (int r_ = 0; r_ < 16; ++r_) { \
                e_[r_] = exp2f(ni_ ? s1_[r_] : s0_[r_]); \
                lpart[ni_] += e_[r_]; \
            } \
            _Pragma("unroll") \
            for (int g_ = 0; g_ < 4; ++g_) { \
                pk_[ni_][g_][0] = __builtin_amdgcn_perm(fbits(e_[4*g_+1]), fbits(e_[4*g_+0]), 0x07060302); \
                pk_[ni_][g_][1] = __builtin_amdgcn_perm(fbits(e_[4*g_+3]), fbits(e_[4*g_+2]), 0x07060302); \
            } \
        } \
        _Pragma("unroll") \
        for (int km_ = 0; km_ < 2; ++km_) { \
            _Pragma("unroll") \
            for (int ni_ = 0; ni_ < 2; ++ni_) { \
                unsigned aO = h ? pk_[ni_][km_*2+1][0] : pk_[ni_][km_*2][0]; \
                unsigned bO = h ? pk_[ni_][km_*2+1][1] : pk_[ni_][km_*2][1]; \
                unsigned aS = h ? pk_[ni_][km_*2][0]   : pk_[ni_][km_*2+1][0]; \
                unsigned bS = h ? pk_[ni_][km_*2][1]   : pk_[ni_][km_*2+1][1]; \
                unsigned xa = (unsigned)__builtin_amdgcn_ds_bpermute(xlane, (int)aS); \
                unsigned xb = (unsigned)__builtin_amdgcn_ds_bpermute(xlane, (int)bS); \
                union { unsigned u[4]; v8bf v; } pu; \
                pu.u[0] = h ? xa : aO; \
                pu.u[1] = h ? xb : bO; \
                pu.u[2] = h ? aO : xa; \
                pu.u[3] = h ? bO : xb; \
                pf[km_][ni_] = pu.v; \
            } \
        } \
    } \
}

__global__ __launch_bounds__(512, 2) void attn_kernel(
    const unsigned short* __restrict__ qf_ws, const unsigned short* __restrict__ kt,
    const unsigned short* __restrict__ vt, const float* __restrict__ x,
    const float* __restrict__ gamma, float* __restrict__ out)
{
    __shared__ __align__(16) unsigned char smem[147456]; // kb 2x32K | vb 2x32K | qlds 16K; red overlays
    __shared__ float l_s[4][128];

    const int bid = blockIdx.x;
    const int bb  = bid & 7;
    const int s   = bid >> 3;        // 128-n strip 0..31
    const int tid = threadIdx.x;
    const int w    = tid >> 6;
    const int lane = tid & 63;
    const int h    = lane >> 5;
    const int l31  = lane & 31;
    const int mq   = w & 3;          // m-quarter (32 m)
    const int nh   = w >> 2;         // n-half (64 n)
    const int vwoff = ((mq >> 1) * 16 + (mq & 1) * 2) * 512;

    unsigned short* kbuf = (unsigned short*)smem;             // [2][16384]
    unsigned short* vbuf = (unsigned short*)(smem + 65536);   // [2][16384]
    unsigned short* qlds = (unsigned short*)(smem + 131072);  // [2 nh][8 kc][lane]{8}

    // ---- Q ni0 fragments in registers (32 VGPR)
    v8bf qf0[8];
    {
        const unsigned short* qb = qf_ws + ((size_t)(bb * 64 + s * 2 + nh)) * 8192;
        #pragma unroll
        for (int kc = 0; kc < 8; ++kc)
            qf0[kc] = *(const v8bf*)(qb + ((size_t)(kc * 64 + lane)) * 8);
    }

    v16f oacc[4][2];   // 128 AGPR
    #pragma unroll
    for (int i = 0; i < 4; ++i)
        #pragma unroll
        for (int j = 0; j < 2; ++j)
            #pragma unroll
            for (int r = 0; r < 16; ++r)
                oacc[i][j][r] = 0.f;
    float lpart[2] = {0.f, 0.f};
    v8bf pf[2][2];     // carried P fragments [km][ni]

    const int xlane = (lane ^ 32) << 2;

    const unsigned short* ktb = kt + (size_t)bb * 524288;
    const unsigned short* vtb = vt + (size_t)bb * 524288;

    // ---- prologue: K0->kb0, K1->kb1, V0->vb0, Q-ni1 -> qlds
    DMAKT(0, 0)
    DMAKT(1, 16384)
    DMAVT(0, 0)
    {
        #pragma unroll
        for (int i_ = 0; i_ < 2; ++i_) {
            const int u_  = i_ * 512 + tid;
            const int nh_ = u_ >> 9, kc_ = (u_ >> 6) & 7, ln_ = u_ & 63;
            __builtin_amdgcn_global_load_lds(
                (gbl_v*)(qf_ws + ((size_t)(bb * 64 + s * 2 + nh_)) * 8192 + (8 + kc_) * 512 + ln_ * 8),
                (lds_v*)(qlds + u_ * 8), 16, 0, 0);
        }
    }
    __syncthreads();

    FUSED(0, 0, 1, 0)   // S(0) + exp + bperm -> pf; no PV

    for (int i = 0; i < 32; i += 2) {
        __syncthreads();                       // kb1/vb0-cycle DMA drained
        if (i + 2 < 32) DMAKT(i + 2, 0)        // into kb0 (S(i) done last body)
        DMAVT(i + 1, 16384)                    // into vb1 (PV(i-1) done last body)
        FUSED(16384, 0, 1, 1)                  // S(i+1) from kb1; PV(i) from vb0

        __syncthreads();
        if (i + 3 < 32) DMAKT(i + 3, 16384)
        if (i + 2 < 32) DMAVT(i + 2, 0)
        FUSED(0, 16384, (i + 2 < 32), 1)       // S(i+2) from kb0; PV(i+1) from vb1
    }

    // ---- softmax denominators
    #pragma unroll
    for (int ni = 0; ni < 2; ++ni) {
        float r = lpart[ni] + __shfl_xor(lpart[ni], 32);
        if (h == 0) l_s[mq][nh * 64 + ni * 32 + l31] = r;
    }
    __syncthreads();

    // ---- O reduction across the 4 mq waves: red[n 128][c 128] stride 133
    float* red = (float*)smem;
    for (int ph = 0; ph < 4; ++ph) {
        if (mq == ph) {
            #pragma unroll
            for (int cb = 0; cb < 4; ++cb)
                #pragma unroll
                for (int ni = 0; ni < 2; ++ni)
                    #pragma unroll
                    for (int g = 0; g < 4; ++g) {
                        float* p = &red[(nh * 64 + ni * 32 + l31) * 133 + cb * 32 + g * 8 + h * 4];
                        v4f val = {oacc[cb][ni][4 * g + 0], oacc[cb][ni][4 * g + 1],
                                   oacc[cb][ni][4 * g + 2], oacc[cb][ni][4 * g + 3]};
                        if (ph == 0) *(v4f*)p = val;
                        else {
                            v4f tv = *(const v4f*)p;
                            tv += val;
                            *(v4f*)p = tv;
                        }
                    }
        }
        __syncthreads();
    }

    // ---- epilogue: out = gamma * O / l + x
    const float g = gamma[0];
    const int   n = tid & 127;
    const int  cg = tid >> 7;
    const float li = 1.0f / ((l_s[0][n] + l_s[1][n]) + (l_s[2][n] + l_s[3][n]));
    #pragma unroll
    for (int j = 0; j < 32; ++j) {
        const int c = cg * 32 + j;
        const size_t idx = ((size_t)(bb * C_ + c)) * N_ + s * 128 + n;
        out[idx] = g * red[n * 133 + c] * li + x[idx];
    }
}

// ---------------------------------------------------------------------------
extern "C" void kernel_launch(void* const* d_in, const int* in_sizes, int n_in,
                              void* d_out, int out_size, void* d_ws, size_t ws_size,
                              hipStream_t stream)
{
    (void)in_sizes; (void)n_in; (void)out_size; (void)ws_size;
    const float* x     = (const float*)d_in[0];
    const float* dw_q  = (const float*)d_in[1];
    const float* pw_q  = (const float*)d_in[2];
    const float* dw_k  = (const float*)d_in[3];
    const float* pw_k  = (const float*)d_in[4];
    const float* dw_v  = (const float*)d_in[5];
    const float* pw_v  = (const float*)d_in[6];
    const float* gamma = (const float*)d_in[7];
    float* out = (float*)d_out;

    unsigned short* qf_ws = (unsigned short*)d_ws;                  // 8 MB
    unsigned short* kt    = qf_ws + (size_t)B_ * N_ * C_;           // 8 MB
    unsigned short* vt    = kt    + (size_t)B_ * N_ * C_;           // 8 MB

    proj_kernel<<<dim3(256), dim3(256), 0, stream>>>(
        x, dw_q, pw_q, dw_k, pw_k, dw_v, pw_v, qf_ws, kt, vt);
    attn_kernel<<<dim3(256), dim3(512), 0, stream>>>(
        qf_ws, kt, vt, x, gamma, out);
}

// Round 11
// 190.298 us; speedup vs baseline: 1.1439x; 1.1439x over previous
//
#include <hip/hip_runtime.h>
#include <hip/hip_bf16.h>

// PAM module R11: q/k/v 1x1 projections -> bf16 MFMA attention -> gamma*out + x.
// R10 post-mortem: in-wave cross-body pipelining spilled (carried pf + dual sacc
// over the 128-VGPR side). R11 gets pipe overlap WITHOUT new per-wave state:
// two INDEPENDENT 4-wave blocks per CU (separate barrier domains) drift in phase,
// so one block's MFMA/LDS overlaps the other's VALU/exp (m114 co-scheduling).
// grid 512 = (b, 64-n strip); block 256 thr = 2 mh x 2 nh(32); subiter 64 m.
// K: double-buffered LDS DMA (16KB tiles). V: L2->register ping-pong (off the
// LDS pipe). oacc 64 AGPR, ~150 VGPR -> fits 2 waves/SIMD with margin.
//
// 32x32x16 layouts (R9-verified): A[i][k]: i=lane&31, k=(lane>>5)*8+e; B same;
// C/D: col=lane&31, row=(reg&3)+8*(reg>>2)+4*(lane>>5).
// Workspace (bf16, frag-major, unchanged since R9):
//   qf_ws[b][strip64][ni2][kc8][lane]{8}   8MB
//   kt   [b][sub64][mh2][kc8][lane]{8}     8MB
//   vt   [b][sub64][cb4][km4][lane]{8}     8MB

typedef __bf16 v8bf __attribute__((ext_vector_type(8)));
typedef float  v4f  __attribute__((ext_vector_type(4)));
typedef float  v16f __attribute__((ext_vector_type(16)));
typedef __attribute__((address_space(3))) void       lds_v;
typedef const __attribute__((address_space(1))) void gbl_v;

#define B_ 8
#define C_ 128
#define N_ 4096
#define LOG2E 1.4426950408889634f

static __device__ __forceinline__ unsigned short f2bf_rne(float f) {
    union { float f; unsigned u; } v; v.f = f;
    return (unsigned short)((v.u + 0x7fffu + ((v.u >> 16) & 1u)) >> 16);
}
static __device__ __forceinline__ unsigned fbits(float f) {
    union { float f; unsigned u; } v; v.f = f; return v.u;
}

// ---------------------------------------------------------------------------
// Kernel 1: unchanged from R10 (proven: absmax 0.0156 incl. LOG2E fold).
// ---------------------------------------------------------------------------
__global__ __launch_bounds__(256, 2) void proj_kernel(
    const float* __restrict__ x,
    const float* __restrict__ dw_q, const float* __restrict__ pw_q,
    const float* __restrict__ dw_k, const float* __restrict__ pw_k,
    const float* __restrict__ dw_v, const float* __restrict__ pw_v,
    unsigned short* __restrict__ qf_ws, unsigned short* __restrict__ kt,
    unsigned short* __restrict__ vt)
{
    __shared__ unsigned short xT[128 * 136];
    __shared__ unsigned short Ws[128 * 136];

    const int bid = blockIdx.x;
    const int bb  = bid & 7;
    const int t   = bid >> 3;
    const int n0  = t * 128;
    const int tid = threadIdx.x;
    const int w    = tid >> 6;
    const int lane = tid & 63;
    const int quad = lane >> 4;
    const int l16  = lane & 15;

    #pragma unroll
    for (int k = 0; k < 16; ++k) {
        const int idx = tid + k * 256;
        const int c  = idx >> 5;
        const int nq = idx & 31;
        float4 f = *(const float4*)(x + ((size_t)(bb * C_ + c)) * N_ + n0 + nq * 4);
        xT[(nq * 4 + 0) * 136 + c] = f2bf_rne(f.x);
        xT[(nq * 4 + 1) * 136 + c] = f2bf_rne(f.y);
        xT[(nq * 4 + 2) * 136 + c] = f2bf_rne(f.z);
        xT[(nq * 4 + 3) * 136 + c] = f2bf_rne(f.w);
    }

    for (int pp = 0; pp < 3; ++pp) {
        __syncthreads();

        const float* pw = (pp == 0) ? pw_q : (pp == 1) ? pw_k : pw_v;
        const float* dw = (pp == 0) ? dw_q : (pp == 1) ? dw_k : dw_v;
        const float wsc = (pp == 0) ? LOG2E : 1.0f;   // softmax via exp2
        #pragma unroll
        for (int k = 0; k < 16; ++k) {
            const int idx = tid + k * 256;
            const int o  = idx >> 5;
            const int c4 = (idx & 31) * 4;
            float4 p4 = *(const float4*)(pw + o * 128 + c4);
            float4 d4 = *(const float4*)(dw + c4);
            unsigned lo = (unsigned)f2bf_rne(p4.x * d4.x * wsc) | ((unsigned)f2bf_rne(p4.y * d4.y * wsc) << 16);
            unsigned hi = (unsigned)f2bf_rne(p4.z * d4.z * wsc) | ((unsigned)f2bf_rne(p4.w * d4.w * wsc) << 16);
            *(unsigned long long*)&Ws[o * 136 + c4] =
                (unsigned long long)lo | ((unsigned long long)hi << 32);
        }
        __syncthreads();

        const unsigned short* As = (pp < 2) ? xT : Ws;
        const unsigned short* Bs = (pp < 2) ? Ws : xT;

        v4f acc[2][8];
        #pragma unroll
        for (int i = 0; i < 2; ++i)
            #pragma unroll
            for (int j = 0; j < 8; ++j)
                acc[i][j] = (v4f){0.f, 0.f, 0.f, 0.f};

        #pragma unroll
        for (int kc = 0; kc < 4; ++kc) {
            v8bf av[2];
            #pragma unroll
            for (int i = 0; i < 2; ++i)
                av[i] = *(const v8bf*)&As[(w * 32 + i * 16 + l16) * 136 + kc * 32 + quad * 8];
            #pragma unroll
            for (int cb = 0; cb < 8; ++cb) {
                v8bf bv = *(const v8bf*)&Bs[(cb * 16 + l16) * 136 + kc * 32 + quad * 8];
                acc[0][cb] = __builtin_amdgcn_mfma_f32_16x16x32_bf16(av[0], bv, acc[0][cb], 0, 0, 0);
                acc[1][cb] = __builtin_amdgcn_mfma_f32_16x16x32_bf16(av[1], bv, acc[1][cb], 0, 0, 0);
            }
        }
        __syncthreads();

        unsigned short* sc = Ws;
        #pragma unroll
        for (int mi = 0; mi < 2; ++mi)
            #pragma unroll
            for (int cb = 0; cb < 8; ++cb)
                #pragma unroll
                for (int r = 0; r < 4; ++r)
                    sc[(w * 32 + mi * 16 + quad * 4 + r) * 136 + cb * 16 + l16] =
                        f2bf_rne(acc[mi][cb][r]);
        __syncthreads();

        if (pp == 0) {
            unsigned short* dst = qf_ws + ((size_t)(bb * 64 + t * 2)) * 8192;
            #pragma unroll
            for (int p = 0; p < 8; ++p) {
                const int u  = p * 256 + tid;
                const int lu = u & 63, kc = (u >> 6) & 7, ni = (u >> 9) & 1, st = u >> 10;
                const int row = st * 64 + ni * 32 + (lu & 31);
                const int col = kc * 16 + (lu >> 5) * 8;
                *(uint4*)(dst + (size_t)u * 8) = *(const uint4*)&sc[row * 136 + col];
            }
        } else if (pp == 1) {
            unsigned short* dst = kt + ((size_t)(bb * 64 + t * 2)) * 8192;
            #pragma unroll
            for (int p = 0; p < 8; ++p) {
                const int u  = p * 256 + tid;
                const int lu = u & 63, kc = (u >> 6) & 7, mh = (u >> 9) & 1, st = u >> 10;
                const int row = st * 64 + mh * 32 + (lu & 31);
                const int col = kc * 16 + (lu >> 5) * 8;
                *(uint4*)(dst + (size_t)u * 8) = *(const uint4*)&sc[row * 136 + col];
            }
        } else {
            unsigned short* dst = vt + ((size_t)(bb * 64 + t * 2)) * 8192;
            #pragma unroll
            for (int p = 0; p < 8; ++p) {
                const int u  = p * 256 + tid;
                const int lu = u & 63, km = (u >> 6) & 3, cb = (u >> 8) & 3, st = u >> 10;
                const int row = cb * 32 + (lu & 31);
                const int col = st * 64 + km * 16 + (lu >> 5) * 8;
                *(uint4*)(dst + (size_t)u * 8) = *(const uint4*)&sc[row * 136 + col];
            }
        }
    }
}

// ---------------------------------------------------------------------------
// Kernel 2: attention. grid 512 = (b = bid&7, 64-n strip = bid>>3).
// 256 thr / 4 waves = 2 mh x 2 nh(32). 64 subiters of 64 m:
//   sync; DMA K(next) -> other buf; load V(next) -> other reg set; compute.
// ---------------------------------------------------------------------------
#define DMAK(TILE, OFF) { \
    const unsigned short* ks_ = ktb + (size_t)(TILE) * 8192; \
    _Pragma("unroll") \
    for (int i_ = 0; i_ < 4; ++i_) { \
        const int u_ = i_ * 256 + tid; \
        __builtin_amdgcn_global_load_lds((gbl_v*)(ks_ + (size_t)u_ * 8), \
                                         (lds_v*)(kbuf + (OFF) + u_ * 8), 16, 0, 0); \
    } \
}

#define LOADV(VF, TILE) { \
    const unsigned short* vp_ = vtb + (size_t)(TILE) * 8192 + (mh * 2) * 512 + lane * 8; \
    _Pragma("unroll") \
    for (int cb_ = 0; cb_ < 4; ++cb_) { \
        VF[cb_ * 2 + 0] = *(const v8bf*)(vp_ + (cb_ * 4 + 0) * 512); \
        VF[cb_ * 2 + 1] = *(const v8bf*)(vp_ + (cb_ * 4 + 1) * 512); \
    } \
}

#define COMPUTE(KOFF, VF) { \
    const unsigned short* kp_ = kbuf + (KOFF) + mh * 4096 + lane * 8; \
    v16f sacc_; \
    _Pragma("unroll") \
    for (int r_ = 0; r_ < 16; ++r_) sacc_[r_] = 0.f; \
    _Pragma("unroll") \
    for (int kc_ = 0; kc_ < 8; ++kc_) { \
        v8bf kf_ = *(const v8bf*)(kp_ + kc_ * 512); \
        sacc_ = __builtin_amdgcn_mfma_f32_32x32x16_bf16(kf_, qf[kc_], sacc_, 0, 0, 0); \
    } \
    float e_[16]; \
    _Pragma("unroll") \
    for (int r_ = 0; r_ < 16; ++r_) { \
        e_[r_] = exp2f(sacc_[r_]); \
        lpart += e_[r_]; \
    } \
    unsigned pk_[4][2]; \
    _Pragma("unroll") \
    for (int g_ = 0; g_ < 4; ++g_) { \
        pk_[g_][0] = __builtin_amdgcn_perm(fbits(e_[4*g_+1]), fbits(e_[4*g_+0]), 0x07060302); \
        pk_[g_][1] = __builtin_amdgcn_perm(fbits(e_[4*g_+3]), fbits(e_[4*g_+2]), 0x07060302); \
    } \
    v8bf pf_[2]; \
    _Pragma("unroll") \
    for (int km_ = 0; km_ < 2; ++km_) { \
        unsigned aO = h ? pk_[km_*2+1][0] : pk_[km_*2][0]; \
        unsigned bO = h ? pk_[km_*2+1][1] : pk_[km_*2][1]; \
        unsigned aS = h ? pk_[km_*2][0]   : pk_[km_*2+1][0]; \
        unsigned bS = h ? pk_[km_*2][1]   : pk_[km_*2+1][1]; \
        unsigned xa = (unsigned)__builtin_amdgcn_ds_bpermute(xlane, (int)aS); \
        unsigned xb = (unsigned)__builtin_amdgcn_ds_bpermute(xlane, (int)bS); \
        union { unsigned u[4]; v8bf v; } pu; \
        pu.u[0] = h ? xa : aO; \
        pu.u[1] = h ? xb : bO; \
        pu.u[2] = h ? aO : xa; \
        pu.u[3] = h ? bO : xb; \
        pf_[km_] = pu.v; \
    } \
    _Pragma("unroll") \
    for (int cb_ = 0; cb_ < 4; ++cb_) { \
        oacc[cb_] = __builtin_amdgcn_mfma_f32_32x32x16_bf16(VF[cb_*2+0], pf_[0], oacc[cb_], 0, 0, 0); \
        oacc[cb_] = __builtin_amdgcn_mfma_f32_32x32x16_bf16(VF[cb_*2+1], pf_[1], oacc[cb_], 0, 0, 0); \
    } \
}

__global__ __launch_bounds__(256, 2) void attn_kernel(
    const unsigned short* __restrict__ qf_ws, const unsigned short* __restrict__ kt,
    const unsigned short* __restrict__ vt, const float* __restrict__ x,
    const float* __restrict__ gamma, float* __restrict__ out)
{
    __shared__ __align__(16) unsigned char smem[34816]; // kbuf 2x16KB; red[64][133] overlay
    __shared__ float l_s[2][64];

    const int bid = blockIdx.x;
    const int bb  = bid & 7;
    const int s   = bid >> 3;        // 64-n strip 0..63
    const int n0  = s * 64;
    const int tid = threadIdx.x;
    const int w    = tid >> 6;       // 4 waves: mh = w&1, nh = w>>1
    const int lane = tid & 63;
    const int h    = lane >> 5;
    const int l31  = lane & 31;
    const int mh   = w & 1;          // m-half (32 m) of 64-m subiter
    const int nh   = w >> 1;         // n-half (32 n) of 64-n strip

    unsigned short* kbuf = (unsigned short*)smem;   // [2][8192] elems

    // ---- Q fragments (n=32), iteration-invariant: 32 VGPR
    v8bf qf[8];
    {
        const unsigned short* qb = qf_ws + ((size_t)(bb * 64 + s)) * 8192 + nh * 4096;
        #pragma unroll
        for (int kc = 0; kc < 8; ++kc)
            qf[kc] = *(const v8bf*)(qb + (size_t)(kc * 512 + lane * 8));
    }

    v16f oacc[4];   // 64 AGPR: O[c=cb*32+..][n=nh*32+l31] over this wave's m-halves
    #pragma unroll
    for (int i = 0; i < 4; ++i)
        #pragma unroll
        for (int r = 0; r < 16; ++r)
            oacc[i][r] = 0.f;
    float lpart = 0.f;

    const int xlane = (lane ^ 32) << 2;

    const unsigned short* ktb = kt + (size_t)bb * 524288;
    const unsigned short* vtb = vt + (size_t)bb * 524288;

    v8bf vfA[8], vfB[8];

    DMAK(0, 0)
    LOADV(vfA, 0)

    for (int si = 0; si < 64; si += 2) {
        __syncthreads();                 // DMA(si) drained; prior readers of other buf done
        if (si + 1 < 64) { DMAK(si + 1, 8192) }
        LOADV(vfB, (si + 1) & 63)
        COMPUTE(0, vfA)
        __syncthreads();
        if (si + 2 < 64) { DMAK(si + 2, 0) }
        LOADV(vfA, (si + 2) & 63)
        COMPUTE(8192, vfB)
    }

    // ---- softmax denominators: wave's partial over its m-half
    {
        float r = lpart + __shfl_xor(lpart, 32);
        if (h == 0) l_s[mh][nh * 32 + l31] = r;
    }
    __syncthreads();   // main loop + l_s done; smem reusable

    // ---- O reduction across the 2 mh waves: red[n 64][c 128] stride 133
    float* red = (float*)smem;
    #pragma unroll
    for (int ph = 0; ph < 2; ++ph) {
        if (mh == ph) {
            #pragma unroll
            for (int cb = 0; cb < 4; ++cb)
                #pragma unroll
                for (int g = 0; g < 4; ++g) {
                    float* p = &red[(nh * 32 + l31) * 133 + cb * 32 + g * 8 + h * 4];
                    v4f val = {oacc[cb][4 * g + 0], oacc[cb][4 * g + 1],
                               oacc[cb][4 * g + 2], oacc[cb][4 * g + 3]};
                    if (ph == 0) *(v4f*)p = val;
                    else {
                        v4f tv = *(const v4f*)p;
                        tv += val;
                        *(v4f*)p = tv;
                    }
                }
        }
        __syncthreads();
    }

    // ---- epilogue: out = gamma * O / l + x   (n = tid&63, coalesced)
    const float g = gamma[0];
    const int   n = tid & 63;
    const int  cg = tid >> 6;        // 0..3
    const float li = 1.0f / (l_s[0][n] + l_s[1][n]);
    #pragma unroll
    for (int j = 0; j < 32; ++j) {
        const int c = cg * 32 + j;
        const size_t idx = ((size_t)(bb * C_ + c)) * N_ + n0 + n;
        out[idx] = g * red[n * 133 + c] * li + x[idx];
    }
}

// ---------------------------------------------------------------------------
extern "C" void kernel_launch(void* const* d_in, const int* in_sizes, int n_in,
                              void* d_out, int out_size, void* d_ws, size_t ws_size,
                              hipStream_t stream)
{
    (void)in_sizes; (void)n_in; (void)out_size; (void)ws_size;
    const float* x     = (const float*)d_in[0];
    const float* dw_q  = (const float*)d_in[1];
    const float* pw_q  = (const float*)d_in[2];
    const float* dw_k  = (const float*)d_in[3];
    const float* pw_k  = (const float*)d_in[4];
    const float* dw_v  = (const float*)d_in[5];
    const float* pw_v  = (const float*)d_in[6];
    const float* gamma = (const float*)d_in[7];
    float* out = (float*)d_out;

    unsigned short* qf_ws = (unsigned short*)d_ws;                  // 8 MB
    unsigned short* kt    = qf_ws + (size_t)B_ * N_ * C_;           // 8 MB
    unsigned short* vt    = kt    + (size_t)B_ * N_ * C_;           // 8 MB

    proj_kernel<<<dim3(256), dim3(256), 0, stream>>>(
        x, dw_q, pw_q, dw_k, pw_k, dw_v, pw_v, qf_ws, kt, vt);
    attn_kernel<<<dim3(512), dim3(256), 0, stream>>>(
        qf_ws, kt, vt, x, gamma, out);
}